// Round 10
// baseline (55.419 us; speedup 1.0000x reference)
//
#include <hip/hip_runtime.h>
#include <hip/hip_bf16.h>

typedef short  short8 __attribute__((ext_vector_type(8)));
typedef float  f32x4  __attribute__((ext_vector_type(4)));
typedef unsigned int u32;
typedef unsigned long long u64;
typedef unsigned short u16;

// ---------- helpers ----------
__device__ __forceinline__ u32 f2bf(float v) {              // fp32 -> bf16 bits (RNE), prep only
    u32 u = __float_as_uint(v);
    return (u + 0x7FFFu + ((u >> 16) & 1u)) >> 16;
}
__device__ __forceinline__ float qround128(float w) {       // round(w*128) clip [-128,127]
    float q = rintf(w * 128.0f);
    return fminf(fmaxf(q, -128.0f), 127.0f);
}
__device__ __forceinline__ u32 cvtpk(float a, float b) {    // v_cvt_pk_bf16_f32
    __hip_bfloat162 h = __float22bfloat162_rn(make_float2(a, b));
    union { __hip_bfloat162 h; u32 u; } cv; cv.h = h; return cv.u;
}
__device__ __forceinline__ float q255(float v) {            // qrelu int: clamp(rndne(v),0,255)
    return fminf(fmaxf(rintf(v), 0.f), 255.f);
}
union FragU { short8 s; u32 u[4]; };
__device__ __forceinline__ short8 pack2(f32x4 a, f32x4 b) {
    FragU f;
    f.u[0] = cvtpk(q255(a[0]), q255(a[1]));
    f.u[1] = cvtpk(q255(a[2]), q255(a[3]));
    f.u[2] = cvtpk(q255(b[0]), q255(b[1]));
    f.u[3] = cvtpk(q255(b[2]), q255(b[3]));
    return f.s;
}
__device__ __forceinline__ f32x4 mfma16(short8 a, short8 b, f32x4 c) {
    return __builtin_amdgcn_mfma_f32_16x16x32_bf16(a, b, c, 0, 0, 0);
}
// async global->LDS, 16B/lane: LDS dst = wave-uniform base + lane*16; global src per-lane
__device__ __forceinline__ void gload16(const float* src, float* lds_dst) {
    __builtin_amdgcn_global_load_lds(
        (const __attribute__((address_space(1))) u32*)src,
        (__attribute__((address_space(3))) u32*)lds_dst,
        16, 0, 0);
}

// ---------- ws layout (byte-identical to verified round 8/9) ----------
__global__ void prep(const float* __restrict__ w1, const float* __restrict__ b1,
                     const float* __restrict__ w2, const float* __restrict__ b2,
                     const float* __restrict__ w3, const float* __restrict__ b3,
                     const float* __restrict__ wo, const float* __restrict__ bo,
                     u16* __restrict__ wsh) {
    int idx = blockIdx.x * 256 + threadIdx.x;      // 32 blocks x 256 = 8192 = 16*512
    if (idx < 16 * 512) {
        int blk = idx >> 9, e = idx & 511;
        int l = e >> 3, j = e & 7;
        int r  = l & 15;
        int gi = l >> 4;
        int fp = 16 * (j >> 2) + 4 * gi + (j & 3); // permuted (L2/L3/out)
        float val = 0.f;
        if (blk < 8) {
            int mt = blk >> 1, ks = blk & 1;
            int fo = mt * 16 + r;
            if (ks == 0) {
                val = 2.0f * qround128(w1[(12 * gi + j) * 64 + fo]);
            } else if (j < 4) {
                val = 2.0f * qround128(w1[(12 * gi + 8 + j) * 64 + fo]);
            } else if (gi == 3 && j == 7) {
                val = 2.0f * qround128(b1[fo]);    // bias slot (activation = 1.0)
            }
        } else if (blk < 12) {
            int bi = blk - 8, mt = bi >> 1, ks = bi & 1;
            int f = ks * 32 + fp, fo = mt * 16 + r;
            val = qround128(w2[f * 32 + fo]) * (1.0f / 128.0f);
        } else if (blk < 14) {
            int mt = blk - 12;
            val = qround128(w3[fp * 32 + mt * 16 + r]) * (1.0f / 128.0f);
        } else {
            float wv = (r < 5) ? wo[fp * 5 + r] * (1.0f / 256.0f) : 0.f;
            u32 hb = f2bf(wv);
            if (blk == 14) { wsh[idx] = (u16)hb; return; }
            val = wv - __uint_as_float(hb << 16);
        }
        wsh[idx] = (u16)f2bf(val);
    }
    if (blockIdx.x == 0) {
        int t = threadIdx.x;
        float* wsf = (float*)(wsh + 8192);
        for (int i = t; i < 32; i += 256) wsf[64 + i]  = 2.0f * qround128(b2[i]);
        for (int i = t; i < 32; i += 256) wsf[96 + i]  = 2.0f * qround128(b3[i]);
        for (int i = t; i < 16; i += 256) wsf[128 + i] = (i < 5) ? bo[i] : 0.f;
    }
}

// ---------- main kernel ----------
// R8/R9-verified math. Round-10 structure: 3 tiles per pack, wave-private LDS
// double buffer filled by global_load_lds with PRE-SWIZZLED per-lane global
// sources so the LDS layout is "lane l's 12 floats contiguous at l*48B":
//   slab float F = 256*s + 4*m  (issue s, lane m) must hold lane l=F/12's
//   element e=F%12  ->  src = x[tile*768 + (l&15)*48 + (l>>4)*12 + e]
// Reads: 3x ds_read_b128 at l*48 (+16,+32): banks (12l+4j)%32 cover all 32
// exactly once per 8 lanes -> ZERO bank conflicts. Counted vmcnt(9) keeps the
// next pack's 9 DMAs in flight across the whole compute phase. No barriers.

__global__ __launch_bounds__(256, 2) void mlp_mfma(const float* __restrict__ x,
                                                   const u16* __restrict__ wsh,
                                                   float* __restrict__ out, int ntiles) {
    // [wave][buf][3 tiles][768 floats] = 4*2*3*768*4B = 73728 B
    __shared__ __align__(16) float smem[4][2][3][768];
    const int tid = threadIdx.x;
    const int wid = tid >> 6, lane = tid & 63;
    const int c = lane & 15, g = lane >> 4;

    // resident weight A-fragments (64 VGPR)
    short8 wf[16];
    const short8* wv = (const short8*)wsh;
    #pragma unroll
    for (int i = 0; i < 16; ++i) wf[i] = wv[i * 64 + lane];

    // biases (b1 folded into L1 K-slot)
    const float* wsf = (const float*)(wsh + 8192);
    f32x4 b2q[2], b3q[2], boq;
    #pragma unroll
    for (int i = 0; i < 2; ++i) b2q[i] = *(const f32x4*)(wsf + 64 + i * 16 + 4 * g);
    #pragma unroll
    for (int i = 0; i < 2; ++i) b3q[i] = *(const f32x4*)(wsf + 96 + i * 16 + 4 * g);
    boq = *(const f32x4*)(wsf + 128 + 4 * g);

    // pre-swizzled per-lane source float-offsets for the 3 issue phases of a tile
    u32 soff[3];
    #pragma unroll
    for (int s = 0; s < 3; ++s) {
        int k = 64 * s + lane;
        int l = k / 3, j = k - 3 * l;          // target lane l, 16B-chunk j
        soff[s] = (u32)((l & 15) * 48 + (l >> 4) * 12 + 4 * j);
    }

    const int npacks = (ntiles + 2) / 3;
    const int gw = blockIdx.x * 4 + wid;
    const int nw = gridDim.x * 4;
    const f32x4 zero4 = {0.f, 0.f, 0.f, 0.f};

    // stage one pack (3 tiles) into buf: 9 DMA issues, swizzled sources
    auto stage = [&](int buf, int pk) {
        #pragma unroll
        for (int i = 0; i < 3; ++i) {
            int tt = 3 * pk + i;
            if (tt >= ntiles) tt = ntiles - 1;           // clamp (uniform)
            const float* tb = x + (size_t)tt * 768;
            #pragma unroll
            for (int s = 0; s < 3; ++s) {
                gload16(tb + soff[s], &smem[wid][buf][i][s * 256]);
            }
        }
    };

    int p = gw;
    int buf = 0;
    if (p < npacks) stage(0, p);

    for (; p < npacks; p += nw) {
        const int pn = p + nw;
        const bool have = pn < npacks;
        if (have) {
            stage(buf ^ 1, pn);
            asm volatile("s_waitcnt vmcnt(9)" ::: "memory");  // cur pack ready; next 9 in flight
        } else {
            asm volatile("s_waitcnt vmcnt(0)" ::: "memory");
        }
        __builtin_amdgcn_sched_barrier(0);

        #pragma unroll
        for (int i = 0; i < 3; ++i) {
            const float* T = &smem[wid][buf][i][0] + lane * 12;   // conflict-free b128 x3
            float4 q0 = *(const float4*)(T);
            float4 q1 = *(const float4*)(T + 4);
            float4 q2 = *(const float4*)(T + 8);
            float v[12] = {q0.x, q0.y, q0.z, q0.w,
                           q1.x, q1.y, q1.z, q1.w,
                           q2.x, q2.y, q2.z, q2.w};

            // hi/lo bf16 split
            FragU bh0, bl0, bh1, bl1;
            #pragma unroll
            for (int q = 0; q < 4; ++q) {
                u32 uu = cvtpk(v[2 * q], v[2 * q + 1]);
                bh0.u[q] = uu;
                float r0 = v[2 * q]     - __uint_as_float(uu << 16);
                float r1 = v[2 * q + 1] - __uint_as_float(uu & 0xFFFF0000u);
                bl0.u[q] = cvtpk(r0, r1);
            }
            #pragma unroll
            for (int q = 0; q < 2; ++q) {
                u32 uu = cvtpk(v[8 + 2 * q], v[9 + 2 * q]);
                bh1.u[q] = uu;
                float r0 = v[8 + 2 * q] - __uint_as_float(uu << 16);
                float r1 = v[9 + 2 * q] - __uint_as_float(uu & 0xFFFF0000u);
                bl1.u[q] = cvtpk(r0, r1);
            }
            bh1.u[2] = 0u;
            bh1.u[3] = (g == 3) ? 0x3F800000u : 0u;   // bias-slot activation 1.0
            bl1.u[2] = 0u; bl1.u[3] = 0u;

            // layer 1: acc = 256*preact (bias via k=63 slot)
            f32x4 acc1[4];
            #pragma unroll
            for (int mt = 0; mt < 4; ++mt) {
                f32x4 ah = mfma16(wf[mt * 2 + 0], bh0.s, zero4);
                ah = mfma16(wf[mt * 2 + 1], bh1.s, ah);
                f32x4 al = mfma16(wf[mt * 2 + 0], bl0.s, zero4);
                al = mfma16(wf[mt * 2 + 1], bl1.s, al);
                acc1[mt] = ah + al;
            }
            short8 p0 = pack2(acc1[0], acc1[1]);
            short8 p1 = pack2(acc1[2], acc1[3]);

            // layer 2 (K=64)
            f32x4 a20 = mfma16(wf[8],  p0, b2q[0]);
            f32x4 a21 = mfma16(wf[9],  p1, zero4);
            f32x4 a22 = mfma16(wf[10], p0, b2q[1]);
            f32x4 a23 = mfma16(wf[11], p1, zero4);
            short8 p2 = pack2(a20 + a21, a22 + a23);

            // layer 3 (K=32)
            f32x4 a30 = mfma16(wf[12], p2, b3q[0]);
            f32x4 a31 = mfma16(wf[13], p2, b3q[1]);
            short8 p3 = pack2(a30, a31);

            // output: wout/256 hi + lo, acc init = bout
            f32x4 aoh = mfma16(wf[14], p3, boq);
            f32x4 aol = mfma16(wf[15], p3, zero4);
            f32x4 ao = aoh + aol;

            int t = 3 * p + i;
            if (t < ntiles) {
                float* orow = out + (size_t)t * 80 + c * 5;
                if (g == 0) {
                    *(float4*)orow = make_float4(ao[0], ao[1], ao[2], ao[3]);
                } else if (g == 1) {
                    orow[4] = ao[0];
                }
            }
        }
        buf ^= 1;
    }
}

extern "C" void kernel_launch(void* const* d_in, const int* in_sizes, int n_in,
                              void* d_out, int out_size, void* d_ws, size_t ws_size,
                              hipStream_t stream) {
    const float* x  = (const float*)d_in[0];
    const float* w1 = (const float*)d_in[1];
    const float* b1 = (const float*)d_in[2];
    const float* w2 = (const float*)d_in[3];
    const float* b2 = (const float*)d_in[4];
    const float* w3 = (const float*)d_in[5];
    const float* b3 = (const float*)d_in[6];
    const float* wo = (const float*)d_in[7];
    const float* bo = (const float*)d_in[8];
    float* out = (float*)d_out;

    int B = in_sizes[0] / 48;
    int ntiles = B / 16;                       // 1e6 -> 62500

    prep<<<32, 256, 0, stream>>>(w1, b1, w2, b2, w3, b3, wo, bo, (u16*)d_ws);

    // exactly-resident grid: 2 blocks/CU x 256 CUs (LDS 73.7KB/block -> 2/CU)
    int blocks = 512;
    mlp_mfma<<<blocks, 256, 0, stream>>>(x, (const u16*)d_ws, out, ntiles);
}

// Round 11
// 53.527 us; speedup vs baseline: 1.0353x; 1.0353x over previous
//
#include <hip/hip_runtime.h>
#include <hip/hip_bf16.h>

typedef short  short8 __attribute__((ext_vector_type(8)));
typedef float  f32x4  __attribute__((ext_vector_type(4)));
typedef unsigned int u32;
typedef unsigned long long u64;
typedef unsigned short u16;

// ---------- helpers ----------
__device__ __forceinline__ u32 f2bf(float v) {              // fp32 -> bf16 bits (RNE), prep only
    u32 u = __float_as_uint(v);
    return (u + 0x7FFFu + ((u >> 16) & 1u)) >> 16;
}
__device__ __forceinline__ float qround128(float w) {       // round(w*128) clip [-128,127]
    float q = rintf(w * 128.0f);
    return fminf(fmaxf(q, -128.0f), 127.0f);
}
__device__ __forceinline__ u32 cvtpk(float a, float b) {    // v_cvt_pk_bf16_f32
    __hip_bfloat162 h = __float22bfloat162_rn(make_float2(a, b));
    union { __hip_bfloat162 h; u32 u; } cv; cv.h = h; return cv.u;
}
__device__ __forceinline__ float q255(float v) {            // qrelu int: clamp(rndne(v),0,255)
    return fminf(fmaxf(rintf(v), 0.f), 255.f);
}
union FragU { short8 s; u32 u[4]; };
__device__ __forceinline__ short8 pack2(f32x4 a, f32x4 b) {
    FragU f;
    f.u[0] = cvtpk(q255(a[0]), q255(a[1]));
    f.u[1] = cvtpk(q255(a[2]), q255(a[3]));
    f.u[2] = cvtpk(q255(b[0]), q255(b[1]));
    f.u[3] = cvtpk(q255(b[2]), q255(b[3]));
    return f.s;
}
__device__ __forceinline__ f32x4 mfma16(short8 a, short8 b, f32x4 c) {
    return __builtin_amdgcn_mfma_f32_16x16x32_bf16(a, b, c, 0, 0, 0);
}
// async global->LDS, 16B/lane: LDS dst = wave-uniform base + lane*16; global src per-lane
__device__ __forceinline__ void gload16(const float* src, float* lds_dst) {
    __builtin_amdgcn_global_load_lds(
        (const __attribute__((address_space(1))) u32*)src,
        (__attribute__((address_space(3))) u32*)lds_dst,
        16, 0, 0);
}

// ---------- ws layout (byte-identical to verified rounds 8-10) ----------
__global__ void prep(const float* __restrict__ w1, const float* __restrict__ b1,
                     const float* __restrict__ w2, const float* __restrict__ b2,
                     const float* __restrict__ w3, const float* __restrict__ b3,
                     const float* __restrict__ wo, const float* __restrict__ bo,
                     u16* __restrict__ wsh) {
    int idx = blockIdx.x * 256 + threadIdx.x;      // 32 blocks x 256 = 8192 = 16*512
    if (idx < 16 * 512) {
        int blk = idx >> 9, e = idx & 511;
        int l = e >> 3, j = e & 7;
        int r  = l & 15;
        int gi = l >> 4;
        int fp = 16 * (j >> 2) + 4 * gi + (j & 3); // permuted (L2/L3/out)
        float val = 0.f;
        if (blk < 8) {
            int mt = blk >> 1, ks = blk & 1;
            int fo = mt * 16 + r;
            if (ks == 0) {
                val = 2.0f * qround128(w1[(12 * gi + j) * 64 + fo]);
            } else if (j < 4) {
                val = 2.0f * qround128(w1[(12 * gi + 8 + j) * 64 + fo]);
            } else if (gi == 3 && j == 7) {
                val = 2.0f * qround128(b1[fo]);    // bias slot (activation = 1.0)
            }
        } else if (blk < 12) {
            int bi = blk - 8, mt = bi >> 1, ks = bi & 1;
            int f = ks * 32 + fp, fo = mt * 16 + r;
            val = qround128(w2[f * 32 + fo]) * (1.0f / 128.0f);
        } else if (blk < 14) {
            int mt = blk - 12;
            val = qround128(w3[fp * 32 + mt * 16 + r]) * (1.0f / 128.0f);
        } else {
            float wv = (r < 5) ? wo[fp * 5 + r] * (1.0f / 256.0f) : 0.f;
            u32 hb = f2bf(wv);
            if (blk == 14) { wsh[idx] = (u16)hb; return; }
            val = wv - __uint_as_float(hb << 16);
        }
        wsh[idx] = (u16)f2bf(val);
    }
    if (blockIdx.x == 0) {
        int t = threadIdx.x;
        float* wsf = (float*)(wsh + 8192);
        for (int i = t; i < 32; i += 256) wsf[64 + i]  = 2.0f * qround128(b2[i]);
        for (int i = t; i < 32; i += 256) wsf[96 + i]  = 2.0f * qround128(b3[i]);
        for (int i = t; i < 16; i += 256) wsf[128 + i] = (i < 5) ? bo[i] : 0.f;
    }
}

// ---------- main kernel ----------
// R9 geometry (2-tile packs, 48KB LDS, 3 waves/SIMD, counted vmcnt(6)), plus:
//  * PRE-SWIZZLED DMA sources (R10-verified): lane l's 12 floats land contiguous
//    at LDS float-offset 12*l -> 3x ds_read_b128, all 32 banks covered per 8
//    lanes -> zero conflicts (R9's reads were 8-way conflicted).
//  * PHASE STAGGER: one-time s_sleep keyed by blockIdx de-phases the waves
//    sharing a SIMD (no barriers -> offset persists), so one wave's MFMA burst
//    overlaps another's VALU burst instead of contending for the same pipe.
//  * s_setprio(1) around MFMA clusters (pays once waves are de-phased).

__global__ __launch_bounds__(256, 3) void mlp_mfma(const float* __restrict__ x,
                                                   const u16* __restrict__ wsh,
                                                   float* __restrict__ out, int ntiles) {
    // [wave][buf][2 tiles x 768 floats] = 4*2*1536*4B = 49152 B
    __shared__ __align__(16) float smem[4][2][1536];
    const int tid = threadIdx.x;
    const int wid = tid >> 6, lane = tid & 63;
    const int c = lane & 15, g = lane >> 4;

    // de-phase waves: ~512-cycle steps by block (once, before any work)
    {
        int ph = blockIdx.x & 3;
        if (ph == 1)      asm volatile("s_sleep 8");
        else if (ph == 2) asm volatile("s_sleep 16");
        else if (ph == 3) asm volatile("s_sleep 24");
    }

    // resident weight A-fragments (64 VGPR)
    short8 wf[16];
    const short8* wv = (const short8*)wsh;
    #pragma unroll
    for (int i = 0; i < 16; ++i) wf[i] = wv[i * 64 + lane];

    // biases (b1 folded into L1 K-slot)
    const float* wsf = (const float*)(wsh + 8192);
    f32x4 b2q[2], b3q[2], boq;
    #pragma unroll
    for (int i = 0; i < 2; ++i) b2q[i] = *(const f32x4*)(wsf + 64 + i * 16 + 4 * g);
    #pragma unroll
    for (int i = 0; i < 2; ++i) b3q[i] = *(const f32x4*)(wsf + 96 + i * 16 + 4 * g);
    boq = *(const f32x4*)(wsf + 128 + 4 * g);

    // pre-swizzled per-lane source float-offsets (R10-verified mapping):
    // issue s, lane m: k=64s+m, l=k/3, j=k%3 -> src off (l&15)*48+(l>>4)*12+4j
    u32 soff[3];
    #pragma unroll
    for (int s = 0; s < 3; ++s) {
        int k = 64 * s + lane;
        int l = k / 3, j = k - 3 * l;
        soff[s] = (u32)((l & 15) * 48 + (l >> 4) * 12 + 4 * j);
    }

    const int npacks = (ntiles + 1) >> 1;
    const int gw = blockIdx.x * 4 + wid;
    const int nw = gridDim.x * 4;
    const f32x4 zero4 = {0.f, 0.f, 0.f, 0.f};

    // stage one pack (2 tiles) into buf: 6 DMA issues, swizzled sources
    auto stage = [&](int buf, int pk) {
        #pragma unroll
        for (int i = 0; i < 2; ++i) {
            int tt = 2 * pk + i;
            if (tt >= ntiles) tt = ntiles - 1;           // clamp (uniform)
            const float* tb = x + (size_t)tt * 768;
            #pragma unroll
            for (int s = 0; s < 3; ++s) {
                gload16(tb + soff[s], &smem[wid][buf][i * 768 + s * 256]);
            }
        }
    };

    int p = gw;
    int buf = 0;
    if (p < npacks) stage(0, p);

    for (; p < npacks; p += nw) {
        const int pn = p + nw;
        const bool have = pn < npacks;
        if (have) {
            stage(buf ^ 1, pn);
            asm volatile("s_waitcnt vmcnt(6)" ::: "memory");  // cur pack ready; next 6 in flight
        } else {
            asm volatile("s_waitcnt vmcnt(0)" ::: "memory");
        }
        __builtin_amdgcn_sched_barrier(0);

        #pragma unroll
        for (int i = 0; i < 2; ++i) {
            const float* T = &smem[wid][buf][i * 768] + lane * 12;   // conflict-free b128 x3
            float4 q0 = *(const float4*)(T);
            float4 q1 = *(const float4*)(T + 4);
            float4 q2 = *(const float4*)(T + 8);
            float v[12] = {q0.x, q0.y, q0.z, q0.w,
                           q1.x, q1.y, q1.z, q1.w,
                           q2.x, q2.y, q2.z, q2.w};

            // hi/lo bf16 split
            FragU bh0, bl0, bh1, bl1;
            #pragma unroll
            for (int q = 0; q < 4; ++q) {
                u32 uu = cvtpk(v[2 * q], v[2 * q + 1]);
                bh0.u[q] = uu;
                float r0 = v[2 * q]     - __uint_as_float(uu << 16);
                float r1 = v[2 * q + 1] - __uint_as_float(uu & 0xFFFF0000u);
                bl0.u[q] = cvtpk(r0, r1);
            }
            #pragma unroll
            for (int q = 0; q < 2; ++q) {
                u32 uu = cvtpk(v[8 + 2 * q], v[9 + 2 * q]);
                bh1.u[q] = uu;
                float r0 = v[8 + 2 * q] - __uint_as_float(uu << 16);
                float r1 = v[9 + 2 * q] - __uint_as_float(uu & 0xFFFF0000u);
                bl1.u[q] = cvtpk(r0, r1);
            }
            bh1.u[2] = 0u;
            bh1.u[3] = (g == 3) ? 0x3F800000u : 0u;   // bias-slot activation 1.0
            bl1.u[2] = 0u; bl1.u[3] = 0u;

            // layer 1: acc = 256*preact (bias via k=63 slot)
            f32x4 acc1[4];
            __builtin_amdgcn_s_setprio(1);
            #pragma unroll
            for (int mt = 0; mt < 4; ++mt) {
                f32x4 ah = mfma16(wf[mt * 2 + 0], bh0.s, zero4);
                ah = mfma16(wf[mt * 2 + 1], bh1.s, ah);
                f32x4 al = mfma16(wf[mt * 2 + 0], bl0.s, zero4);
                al = mfma16(wf[mt * 2 + 1], bl1.s, al);
                acc1[mt] = ah + al;
            }
            __builtin_amdgcn_s_setprio(0);
            short8 p0 = pack2(acc1[0], acc1[1]);
            short8 p1 = pack2(acc1[2], acc1[3]);

            // layer 2 (K=64)
            __builtin_amdgcn_s_setprio(1);
            f32x4 a20 = mfma16(wf[8],  p0, b2q[0]);
            f32x4 a21 = mfma16(wf[9],  p1, zero4);
            f32x4 a22 = mfma16(wf[10], p0, b2q[1]);
            f32x4 a23 = mfma16(wf[11], p1, zero4);
            __builtin_amdgcn_s_setprio(0);
            short8 p2 = pack2(a20 + a21, a22 + a23);

            // layer 3 (K=32)
            __builtin_amdgcn_s_setprio(1);
            f32x4 a30 = mfma16(wf[12], p2, b3q[0]);
            f32x4 a31 = mfma16(wf[13], p2, b3q[1]);
            __builtin_amdgcn_s_setprio(0);
            short8 p3 = pack2(a30, a31);

            // output: wout/256 hi + lo, acc init = bout
            __builtin_amdgcn_s_setprio(1);
            f32x4 aoh = mfma16(wf[14], p3, boq);
            f32x4 aol = mfma16(wf[15], p3, zero4);
            __builtin_amdgcn_s_setprio(0);
            f32x4 ao = aoh + aol;

            int t = 2 * p + i;
            if (t < ntiles) {
                float* orow = out + (size_t)t * 80 + c * 5;
                if (g == 0) {
                    *(float4*)orow = make_float4(ao[0], ao[1], ao[2], ao[3]);
                } else if (g == 1) {
                    orow[4] = ao[0];
                }
            }
        }
        buf ^= 1;
    }
}

extern "C" void kernel_launch(void* const* d_in, const int* in_sizes, int n_in,
                              void* d_out, int out_size, void* d_ws, size_t ws_size,
                              hipStream_t stream) {
    const float* x  = (const float*)d_in[0];
    const float* w1 = (const float*)d_in[1];
    const float* b1 = (const float*)d_in[2];
    const float* w2 = (const float*)d_in[3];
    const float* b2 = (const float*)d_in[4];
    const float* w3 = (const float*)d_in[5];
    const float* b3 = (const float*)d_in[6];
    const float* wo = (const float*)d_in[7];
    const float* bo = (const float*)d_in[8];
    float* out = (float*)d_out;

    int B = in_sizes[0] / 48;
    int ntiles = B / 16;                       // 1e6 -> 62500
    int npacks = (ntiles + 1) / 2;             // -> 31250

    prep<<<32, 256, 0, stream>>>(w1, b1, w2, b2, w3, b3, wo, bo, (u16*)d_ws);

    int blocks = (npacks + 3) / 4;
    if (blocks > 2048) blocks = 2048;
    mlp_mfma<<<blocks, 256, 0, stream>>>(x, (const u16*)d_ws, out, ntiles);
}

// Round 12
// 51.428 us; speedup vs baseline: 1.0776x; 1.0408x over previous
//
#include <hip/hip_runtime.h>
#include <hip/hip_bf16.h>

typedef short  short8 __attribute__((ext_vector_type(8)));
typedef float  f32x4  __attribute__((ext_vector_type(4)));
typedef unsigned int u32;
typedef unsigned long long u64;
typedef unsigned short u16;

// ---------- helpers ----------
__device__ __forceinline__ u32 f2bf(float v) {              // fp32 -> bf16 bits (RNE), prep only
    u32 u = __float_as_uint(v);
    return (u + 0x7FFFu + ((u >> 16) & 1u)) >> 16;
}
__device__ __forceinline__ float qround128(float w) {       // round(w*128) clip [-128,127]
    float q = rintf(w * 128.0f);
    return fminf(fmaxf(q, -128.0f), 127.0f);
}
__device__ __forceinline__ u32 cvtpk(float a, float b) {    // v_cvt_pk_bf16_f32
    __hip_bfloat162 h = __float22bfloat162_rn(make_float2(a, b));
    union { __hip_bfloat162 h; u32 u; } cv; cv.h = h; return cv.u;
}
__device__ __forceinline__ float q255(float v) {            // qrelu int: clamp(rndne(v),0,255)
    return fminf(fmaxf(rintf(v), 0.f), 255.f);
}
union FragU { short8 s; u32 u[4]; };
__device__ __forceinline__ short8 pack2(f32x4 a, f32x4 b) {
    FragU f;
    f.u[0] = cvtpk(q255(a[0]), q255(a[1]));
    f.u[1] = cvtpk(q255(a[2]), q255(a[3]));
    f.u[2] = cvtpk(q255(b[0]), q255(b[1]));
    f.u[3] = cvtpk(q255(b[2]), q255(b[3]));
    return f.s;
}
__device__ __forceinline__ f32x4 mfma16(short8 a, short8 b, f32x4 c) {
    return __builtin_amdgcn_mfma_f32_16x16x32_bf16(a, b, c, 0, 0, 0);
}
// async global->LDS, 16B per lane: LDS dest is wave-uniform base + lane*16,
// global src is per-lane. (learn_hip m97/m104 semantics)
__device__ __forceinline__ void gload16(const float* src, float* lds_dst) {
    __builtin_amdgcn_global_load_lds(
        (const __attribute__((address_space(1))) u32*)src,
        (__attribute__((address_space(3))) u32*)lds_dst,
        16, 0, 0);
}

// ---------- ws layout (byte-identical to verified round 8) ----------
__global__ void prep(const float* __restrict__ w1, const float* __restrict__ b1,
                     const float* __restrict__ w2, const float* __restrict__ b2,
                     const float* __restrict__ w3, const float* __restrict__ b3,
                     const float* __restrict__ wo, const float* __restrict__ bo,
                     u16* __restrict__ wsh) {
    int idx = blockIdx.x * 256 + threadIdx.x;      // 32 blocks x 256 = 8192 = 16*512
    if (idx < 16 * 512) {
        int blk = idx >> 9, e = idx & 511;
        int l = e >> 3, j = e & 7;
        int r  = l & 15;
        int gi = l >> 4;
        int fp = 16 * (j >> 2) + 4 * gi + (j & 3); // permuted (L2/L3/out)
        float val = 0.f;
        if (blk < 8) {
            int mt = blk >> 1, ks = blk & 1;
            int fo = mt * 16 + r;
            if (ks == 0) {
                val = 2.0f * qround128(w1[(12 * gi + j) * 64 + fo]);
            } else if (j < 4) {
                val = 2.0f * qround128(w1[(12 * gi + 8 + j) * 64 + fo]);
            } else if (gi == 3 && j == 7) {
                val = 2.0f * qround128(b1[fo]);    // bias slot (activation = 1.0)
            }
        } else if (blk < 12) {
            int bi = blk - 8, mt = bi >> 1, ks = bi & 1;
            int f = ks * 32 + fp, fo = mt * 16 + r;
            val = qround128(w2[f * 32 + fo]) * (1.0f / 128.0f);
        } else if (blk < 14) {
            int mt = blk - 12;
            val = qround128(w3[fp * 32 + mt * 16 + r]) * (1.0f / 128.0f);
        } else {
            float wv = (r < 5) ? wo[fp * 5 + r] * (1.0f / 256.0f) : 0.f;
            u32 hb = f2bf(wv);
            if (blk == 14) { wsh[idx] = (u16)hb; return; }
            val = wv - __uint_as_float(hb << 16);
        }
        wsh[idx] = (u16)f2bf(val);
    }
    if (blockIdx.x == 0) {
        int t = threadIdx.x;
        float* wsf = (float*)(wsh + 8192);
        for (int i = t; i < 32; i += 256) wsf[64 + i]  = 2.0f * qround128(b2[i]);
        for (int i = t; i < 32; i += 256) wsf[96 + i]  = 2.0f * qround128(b3[i]);
        for (int i = t; i < 16; i += 256) wsf[128 + i] = (i < 5) ? bo[i] : 0.f;
    }
}

// ---------- main kernel ----------
// Best-known configuration (round 9, 51.37 us): R8-verified register pipeline +
// wave-private LDS double-buffered staging via global_load_lds with COUNTED
// vmcnt(6): next pack's 6 DMA loads stay in flight across the whole compute
// phase; payload uses zero VGPRs -> 3 waves/SIMD. No barriers (wave-private
// slabs), no cross-lane ops.
// Falsified-levers ledger (R4-R11): prefetch hoist, 2-tile reg ILP, occupancy
// 2->3, chain-splitting, 3-tile packs, conflict-free LDS swizzle, phase
// stagger, s_setprio -- all null or negative. Plateau ~51.4 us vs 34 us
// pure-HBM floor; structure-independent.

__global__ __launch_bounds__(256, 3) void mlp_mfma(const float* __restrict__ x,
                                                   const u16* __restrict__ wsh,
                                                   float* __restrict__ out, int ntiles) {
    // [wave][buf][2 tiles x 768 floats] = 4*2*1536*4B = 49152 B
    __shared__ __align__(16) float smem[4][2][1536];
    const int tid = threadIdx.x;
    const int wid = tid >> 6, lane = tid & 63;
    const int c = lane & 15, g = lane >> 4;

    // resident weight A-fragments (64 VGPR)
    short8 wf[16];
    const short8* wv = (const short8*)wsh;
    #pragma unroll
    for (int i = 0; i < 16; ++i) wf[i] = wv[i * 64 + lane];

    // biases (b1 folded into L1 K-slot)
    const float* wsf = (const float*)(wsh + 8192);
    f32x4 b2q[2], b3q[2], boq;
    #pragma unroll
    for (int i = 0; i < 2; ++i) b2q[i] = *(const f32x4*)(wsf + 64 + i * 16 + 4 * g);
    #pragma unroll
    for (int i = 0; i < 2; ++i) b3q[i] = *(const f32x4*)(wsf + 96 + i * 16 + 4 * g);
    boq = *(const f32x4*)(wsf + 128 + 4 * g);

    const int npacks = (ntiles + 1) >> 1;
    const int gw = blockIdx.x * 4 + wid;
    const int nw = gridDim.x * 4;
    const f32x4 zero4 = {0.f, 0.f, 0.f, 0.f};
    const int roff = c * 48 + g * 12;              // lane's floats within a tile

    // stage one pack (2 consecutive tiles = 6144B contiguous) into buf
    auto stage = [&](int buf, int pk) {
        #pragma unroll
        for (int s = 0; s < 6; ++s) {
            int tt = 2 * pk + (s >= 3 ? 1 : 0);
            if (tt >= ntiles) tt = ntiles - 1;     // clamp (uniform)
            const float* src = x + (size_t)tt * 768 + (s % 3) * 256 + lane * 4;
            gload16(src, &smem[wid][buf][s * 256]);
        }
    };

    int p = gw;
    int buf = 0;
    if (p < npacks) stage(0, p);

    for (; p < npacks; p += nw) {
        const int pn = p + nw;
        const bool have = pn < npacks;
        if (have) {
            stage(buf ^ 1, pn);
            asm volatile("s_waitcnt vmcnt(6)" ::: "memory");   // prev 6 DMA done; new 6 in flight
        } else {
            asm volatile("s_waitcnt vmcnt(0)" ::: "memory");
        }
        __builtin_amdgcn_sched_barrier(0);

        #pragma unroll
        for (int i = 0; i < 2; ++i) {
            const float* T = &smem[wid][buf][i * 768];
            float4 q0 = *(const float4*)(T + roff);
            float4 q1 = *(const float4*)(T + roff + 4);
            float4 q2 = *(const float4*)(T + roff + 8);
            float v[12] = {q0.x, q0.y, q0.z, q0.w,
                           q1.x, q1.y, q1.z, q1.w,
                           q2.x, q2.y, q2.z, q2.w};

            // hi/lo bf16 split
            FragU bh0, bl0, bh1, bl1;
            #pragma unroll
            for (int q = 0; q < 4; ++q) {
                u32 uu = cvtpk(v[2 * q], v[2 * q + 1]);
                bh0.u[q] = uu;
                float r0 = v[2 * q]     - __uint_as_float(uu << 16);
                float r1 = v[2 * q + 1] - __uint_as_float(uu & 0xFFFF0000u);
                bl0.u[q] = cvtpk(r0, r1);
            }
            #pragma unroll
            for (int q = 0; q < 2; ++q) {
                u32 uu = cvtpk(v[8 + 2 * q], v[9 + 2 * q]);
                bh1.u[q] = uu;
                float r0 = v[8 + 2 * q] - __uint_as_float(uu << 16);
                float r1 = v[9 + 2 * q] - __uint_as_float(uu & 0xFFFF0000u);
                bl1.u[q] = cvtpk(r0, r1);
            }
            bh1.u[2] = 0u;
            bh1.u[3] = (g == 3) ? 0x3F800000u : 0u;   // bias-slot activation 1.0
            bl1.u[2] = 0u; bl1.u[3] = 0u;

            // layer 1: acc = 256*preact (bias via k=63 slot)
            f32x4 acc1[4];
            #pragma unroll
            for (int mt = 0; mt < 4; ++mt) {
                f32x4 ah = mfma16(wf[mt * 2 + 0], bh0.s, zero4);
                ah = mfma16(wf[mt * 2 + 1], bh1.s, ah);
                f32x4 al = mfma16(wf[mt * 2 + 0], bl0.s, zero4);
                al = mfma16(wf[mt * 2 + 1], bl1.s, al);
                acc1[mt] = ah + al;
            }
            short8 p0 = pack2(acc1[0], acc1[1]);
            short8 p1 = pack2(acc1[2], acc1[3]);

            // layer 2 (K=64)
            f32x4 a20 = mfma16(wf[8],  p0, b2q[0]);
            f32x4 a21 = mfma16(wf[9],  p1, zero4);
            f32x4 a22 = mfma16(wf[10], p0, b2q[1]);
            f32x4 a23 = mfma16(wf[11], p1, zero4);
            short8 p2 = pack2(a20 + a21, a22 + a23);

            // layer 3 (K=32)
            f32x4 a30 = mfma16(wf[12], p2, b3q[0]);
            f32x4 a31 = mfma16(wf[13], p2, b3q[1]);
            short8 p3 = pack2(a30, a31);

            // output: wout/256 hi + lo, acc init = bout
            f32x4 aoh = mfma16(wf[14], p3, boq);
            f32x4 aol = mfma16(wf[15], p3, zero4);
            f32x4 ao = aoh + aol;

            int t = 2 * p + i;
            if (t < ntiles) {
                float* orow = out + (size_t)t * 80 + c * 5;
                if (g == 0) {
                    *(float4*)orow = make_float4(ao[0], ao[1], ao[2], ao[3]);
                } else if (g == 1) {
                    orow[4] = ao[0];
                }
            }
        }
        buf ^= 1;
    }
}

extern "C" void kernel_launch(void* const* d_in, const int* in_sizes, int n_in,
                              void* d_out, int out_size, void* d_ws, size_t ws_size,
                              hipStream_t stream) {
    const float* x  = (const float*)d_in[0];
    const float* w1 = (const float*)d_in[1];
    const float* b1 = (const float*)d_in[2];
    const float* w2 = (const float*)d_in[3];
    const float* b2 = (const float*)d_in[4];
    const float* w3 = (const float*)d_in[5];
    const float* b3 = (const float*)d_in[6];
    const float* wo = (const float*)d_in[7];
    const float* bo = (const float*)d_in[8];
    float* out = (float*)d_out;

    int B = in_sizes[0] / 48;
    int ntiles = B / 16;                       // 1e6 -> 62500
    int npacks = (ntiles + 1) / 2;             // -> 31250

    prep<<<32, 256, 0, stream>>>(w1, b1, w2, b2, w3, b3, wo, bo, (u16*)d_ws);

    int blocks = (npacks + 3) / 4;
    if (blocks > 2048) blocks = 2048;
    mlp_mfma<<<blocks, 256, 0, stream>>>(x, (const u16*)d_ws, out, ntiles);
}